// Round 1
// baseline (2641.809 us; speedup 1.0000x reference)
//
#include <hip/hip_runtime.h>
#include <hip/hip_bf16.h>
#include <math.h>

#define EPS 1e-5f

// ---------------- GEMM: C[M,N] = A[M,K] @ W[N,K]^T (+bias) (+relu) ----------------
// A row-major M x K; W row-major N x K (so both read along K, coalesced).
// Tile 64x64, K-step 32, 256 threads, 4x4 acc per thread.
template<bool RELU, bool HAS_BIAS>
__global__ __launch_bounds__(256) void gemm_k(const float* __restrict__ A,
                                              const float* __restrict__ W,
                                              const float* __restrict__ bias,
                                              float* __restrict__ C,
                                              int M, int N, int K) {
    __shared__ float As[64][33];
    __shared__ float Ws[64][33];
    const int bx = blockIdx.x * 64;   // N
    const int by = blockIdx.y * 64;   // M
    const int tid = threadIdx.x;
    const int tx = tid & 15;          // col group
    const int ty = tid >> 4;          // row group

    float acc[4][4] = {};

    for (int k0 = 0; k0 < K; k0 += 32) {
        #pragma unroll
        for (int i = tid; i < 64 * 32; i += 256) {
            int r = i >> 5, c = i & 31;
            As[r][c] = A[(size_t)(by + r) * K + k0 + c];
            Ws[r][c] = W[(size_t)(bx + r) * K + k0 + c];
        }
        __syncthreads();
        #pragma unroll
        for (int kk = 0; kk < 32; ++kk) {
            float a[4], w[4];
            #pragma unroll
            for (int i = 0; i < 4; ++i) a[i] = As[ty * 4 + i][kk];
            #pragma unroll
            for (int j = 0; j < 4; ++j) w[j] = Ws[tx * 4 + j][kk];
            #pragma unroll
            for (int i = 0; i < 4; ++i)
                #pragma unroll
                for (int j = 0; j < 4; ++j)
                    acc[i][j] += a[i] * w[j];
        }
        __syncthreads();
    }

    #pragma unroll
    for (int i = 0; i < 4; ++i) {
        int row = by + ty * 4 + i;
        #pragma unroll
        for (int j = 0; j < 4; ++j) {
            int col = bx + tx * 4 + j;
            float v = acc[i][j];
            if (HAS_BIAS) v += bias[col];
            if (RELU) v = fmaxf(v, 0.0f);
            C[(size_t)row * N + col] = v;
        }
    }
}

// ---------------- RoPE in-place: one thread per (b, t, h) row of 64 ----------------
// out[j]    = x[2j]*c[j]   - x[2j+1]*s[j]
// out[32+j] = x[2j+1]*c[j] + x[2j]*s[j]
// where s = dis[0:32], c = dis[32:64]
__global__ __launch_bounds__(256) void rope_k(float* __restrict__ x,
                                              const float* __restrict__ dis,
                                              int rows) {
    int r = blockIdx.x * blockDim.x + threadIdx.x;
    if (r >= rows) return;
    const float* d = dis + (size_t)r * 64;
    float* xr = x + (size_t)r * 64;
    float buf[64];
    #pragma unroll
    for (int j = 0; j < 32; ++j) {
        float s = d[j], c = d[32 + j];
        float x0 = xr[2 * j], x1 = xr[2 * j + 1];
        buf[j]      = x0 * c - x1 * s;
        buf[32 + j] = x1 * c + x0 * s;
    }
    #pragma unroll
    for (int j = 0; j < 64; ++j) xr[j] = buf[j];
}

// ---------------- Attention: per block 8 queries x all keys ----------------
// Q: (B, LQ, H, 64), K/V: (B, LM, H, 64), O: (B, LQ, H, 64). scale = 1/8.
template<int LM, bool CAUSAL>
__global__ __launch_bounds__(256) void attn_k(const float* __restrict__ Q,
                                              const float* __restrict__ K,
                                              const float* __restrict__ V,
                                              float* __restrict__ O,
                                              int H, int LQ) {
    constexpr int QT = 8;
    const int nqt = LQ / QT;
    int bid = blockIdx.x;
    int qt = bid % nqt;
    int h  = (bid / nqt) % H;
    int b  = bid / (nqt * H);
    int q0 = qt * QT;

    __shared__ float Qs[QT][64];
    __shared__ float Ks[64][65];
    __shared__ float Sc[QT][LM];

    const int tid = threadIdx.x;

    // load Q tile
    #pragma unroll
    for (int i = tid; i < QT * 64; i += 256) {
        int qi = i >> 6, d = i & 63;
        Qs[qi][d] = Q[(((size_t)b * LQ + q0 + qi) * H + h) * 64 + d];
    }
    __syncthreads();

    const float scale = 0.125f;

    // scores
    for (int m0 = 0; m0 < LM; m0 += 64) {
        #pragma unroll
        for (int i = tid; i < 64 * 64; i += 256) {
            int m = i >> 6, d = i & 63;
            Ks[m][d] = K[(((size_t)b * LM + m0 + m) * H + h) * 64 + d];
        }
        __syncthreads();
        #pragma unroll
        for (int it = 0; it < 2; ++it) {
            int i = tid + it * 256;
            int qi = i >> 6, m = i & 63;
            float sum = 0.0f;
            #pragma unroll
            for (int d = 0; d < 64; ++d) sum += Qs[qi][d] * Ks[m][d];
            bool valid = (!CAUSAL) || (m0 + m <= q0 + qi);
            Sc[qi][m0 + m] = valid ? sum * scale : -INFINITY;
        }
        __syncthreads();
    }

    // softmax: 4 waves, each wave does 2 rows
    int wave = tid >> 6, lane = tid & 63;
    #pragma unroll
    for (int rr = 0; rr < 2; ++rr) {
        int qi = wave * 2 + rr;
        float mx = -INFINITY;
        for (int m = lane; m < LM; m += 64) mx = fmaxf(mx, Sc[qi][m]);
        #pragma unroll
        for (int o = 32; o >= 1; o >>= 1) mx = fmaxf(mx, __shfl_xor(mx, o));
        float sm = 0.0f;
        for (int m = lane; m < LM; m += 64) {
            float p = __expf(Sc[qi][m] - mx);
            Sc[qi][m] = p;
            sm += p;
        }
        #pragma unroll
        for (int o = 32; o >= 1; o >>= 1) sm += __shfl_xor(sm, o);
        float inv = 1.0f / sm;
        for (int m = lane; m < LM; m += 64) Sc[qi][m] *= inv;
    }
    __syncthreads();

    // PV
    float acc[2] = {0.0f, 0.0f};
    for (int m0 = 0; m0 < LM; m0 += 64) {
        #pragma unroll
        for (int i = tid; i < 64 * 64; i += 256) {
            int m = i >> 6, d = i & 63;
            Ks[m][d] = V[(((size_t)b * LM + m0 + m) * H + h) * 64 + d];
        }
        __syncthreads();
        #pragma unroll
        for (int it = 0; it < 2; ++it) {
            int i = tid + it * 256;
            int qi = i >> 6, d = i & 63;
            float s = acc[it];
            #pragma unroll
            for (int m = 0; m < 64; ++m) s += Sc[qi][m0 + m] * Ks[m][d];
            acc[it] = s;
        }
        __syncthreads();
    }

    #pragma unroll
    for (int it = 0; it < 2; ++it) {
        int i = tid + it * 256;
        int qi = i >> 6, d = i & 63;
        O[(((size_t)b * LQ + q0 + qi) * H + h) * 64 + d] = acc[it];
    }
}

// ---------------- deep_norm: out = LN(x*2 + post) * g + b, row = 512 ----------------
__global__ __launch_bounds__(256) void deepnorm_k(const float* __restrict__ x,
                                                  const float* __restrict__ post,
                                                  const float* __restrict__ g,
                                                  const float* __restrict__ b,
                                                  float* __restrict__ out) {
    int row = blockIdx.x;
    int tid = threadIdx.x;
    const float* xr = x + (size_t)row * 512;
    const float* pr = post + (size_t)row * 512;
    float v0 = xr[tid] * 2.0f + pr[tid];
    float v1 = xr[tid + 256] * 2.0f + pr[tid + 256];

    __shared__ float red[4];
    int wave = tid >> 6, lane = tid & 63;

    float s = v0 + v1;
    #pragma unroll
    for (int o = 32; o >= 1; o >>= 1) s += __shfl_xor(s, o);
    if (lane == 0) red[wave] = s;
    __syncthreads();
    float mean = (red[0] + red[1] + red[2] + red[3]) * (1.0f / 512.0f);

    float d0 = v0 - mean, d1 = v1 - mean;
    float vs = d0 * d0 + d1 * d1;
    #pragma unroll
    for (int o = 32; o >= 1; o >>= 1) vs += __shfl_xor(vs, o);
    __syncthreads();
    if (lane == 0) red[wave] = vs;
    __syncthreads();
    float var = (red[0] + red[1] + red[2] + red[3]) * (1.0f / 512.0f);
    float inv = rsqrtf(var + EPS);

    out[(size_t)row * 512 + tid]       = d0 * inv * g[tid] + b[tid];
    out[(size_t)row * 512 + tid + 256] = d1 * inv * g[tid + 256] + b[tid + 256];
}

__global__ void copy_a_k(const float* __restrict__ A, float* __restrict__ out) {
    out[0] = A[0];
}

// ---------------- launch ----------------
extern "C" void kernel_launch(void* const* d_in, const int* in_sizes, int n_in,
                              void* d_out, int out_size, void* d_ws, size_t ws_size,
                              hipStream_t stream) {
    const float* tgt  = (const float*)d_in[0];
    const float* mem  = (const float*)d_in[1];
    const float* dis_k1 = (const float*)d_in[2];   // glycan_mass
    const float* dis_q1 = (const float*)d_in[3];   // glycan_query_mass
    const float* dis_q2 = (const float*)d_in[4];   // glycan_crossattn_mass
    const float* dis_k2 = (const float*)d_in[5];   // node_mass_emb
    const float* A_in   = (const float*)d_in[10];
    const float* wq1 = (const float*)d_in[11]; const float* bq1 = (const float*)d_in[12];
    const float* wk1 = (const float*)d_in[13]; const float* bk1 = (const float*)d_in[14];
    const float* wv1 = (const float*)d_in[15]; const float* bv1 = (const float*)d_in[16];
    const float* wo1 = (const float*)d_in[17]; const float* bo1 = (const float*)d_in[18];
    const float* ln1g = (const float*)d_in[19]; const float* ln1b = (const float*)d_in[20];
    const float* wq2 = (const float*)d_in[21]; const float* bq2 = (const float*)d_in[22];
    const float* wk2 = (const float*)d_in[23]; const float* bk2 = (const float*)d_in[24];
    const float* wv2 = (const float*)d_in[25]; const float* bv2 = (const float*)d_in[26];
    const float* wo2 = (const float*)d_in[27]; const float* bo2 = (const float*)d_in[28];
    const float* ln2g = (const float*)d_in[29]; const float* ln2b = (const float*)d_in[30];
    const float* wff1 = (const float*)d_in[31]; const float* wff2 = (const float*)d_in[32];
    const float* ln3g = (const float*)d_in[33]; const float* ln3b = (const float*)d_in[34];

    auto at = [&](size_t mb) { return (float*)((char*)d_ws + mb * 1024 * 1024); };
    float* x1   = at(0);    // 4MB  (B*LT*HID)
    float* x2   = at(4);    // 4MB
    float* post = at(8);    // 4MB
    float* q1   = at(12);   // 4MB
    float* k1   = at(16);   // 4MB
    float* v1   = at(20);   // 4MB
    float* att1 = at(24);   // 4MB
    float* q2   = at(12);   // 8MB  (reuse: q1/k1 dead)
    float* k2   = at(20);   // 16MB (reuse: v1/att1 dead by then)
    float* v2   = at(36);   // 16MB
    float* att2 = at(52);   // 8MB
    float* ffh  = at(12);   // 16MB (reuse: q2/k2 dead)

    float* out = (float*)d_out;

    // ---- Phase 1: self-attention ----
    gemm_k<false, true><<<dim3(512 / 64, 2048 / 64), 256, 0, stream>>>(tgt, wq1, bq1, q1, 2048, 512, 512);
    gemm_k<false, true><<<dim3(512 / 64, 2048 / 64), 256, 0, stream>>>(tgt, wk1, bk1, k1, 2048, 512, 512);
    gemm_k<false, true><<<dim3(512 / 64, 2048 / 64), 256, 0, stream>>>(tgt, wv1, bv1, v1, 2048, 512, 512);
    rope_k<<<16384 / 256, 256, 0, stream>>>(q1, dis_q1, 16384);
    rope_k<<<16384 / 256, 256, 0, stream>>>(k1, dis_k1, 16384);
    attn_k<512, true><<<4 * 8 * 64, 256, 0, stream>>>(q1, k1, v1, att1, 8, 512);
    gemm_k<false, true><<<dim3(512 / 64, 2048 / 64), 256, 0, stream>>>(att1, wo1, bo1, post, 2048, 512, 512);
    deepnorm_k<<<2048, 256, 0, stream>>>(tgt, post, ln1g, ln1b, x1);

    // ---- Phase 2: cross-attention ----
    gemm_k<false, true><<<dim3(1024 / 64, 2048 / 64), 256, 0, stream>>>(x1, wq2, bq2, q2, 2048, 1024, 512);
    gemm_k<false, true><<<dim3(1024 / 64, 4096 / 64), 256, 0, stream>>>(mem, wk2, bk2, k2, 4096, 1024, 512);
    gemm_k<false, true><<<dim3(1024 / 64, 4096 / 64), 256, 0, stream>>>(mem, wv2, bv2, v2, 4096, 1024, 512);
    rope_k<<<32768 / 256, 256, 0, stream>>>(q2, dis_q2, 32768);
    rope_k<<<65536 / 256, 256, 0, stream>>>(k2, dis_k2, 65536);
    attn_k<1024, false><<<4 * 16 * 64, 256, 0, stream>>>(q2, k2, v2, att2, 16, 512);
    gemm_k<false, true><<<dim3(512 / 64, 2048 / 64), 256, 0, stream>>>(att2, wo2, bo2, post, 2048, 512, 1024);
    deepnorm_k<<<2048, 256, 0, stream>>>(x1, post, ln2g, ln2b, x2);

    // ---- Phase 3: FFN ----
    gemm_k<true, false><<<dim3(2048 / 64, 2048 / 64), 256, 0, stream>>>(x2, wff1, nullptr, ffh, 2048, 2048, 512);
    gemm_k<false, false><<<dim3(512 / 64, 2048 / 64), 256, 0, stream>>>(ffh, wff2, nullptr, post, 2048, 512, 2048);
    deepnorm_k<<<2048, 256, 0, stream>>>(x2, post, ln3g, ln3b, out);

    copy_a_k<<<1, 1, 0, stream>>>(A_in, out + 2048 * 512);
}

// Round 2
// 1454.538 us; speedup vs baseline: 1.8163x; 1.8163x over previous
//
#include <hip/hip_runtime.h>
#include <hip/hip_bf16.h>
#include <math.h>

#define EPS 1e-5f

typedef __attribute__((ext_vector_type(8))) __bf16 bf16x8;
typedef __attribute__((ext_vector_type(4))) float f32x4;

// ---------------- GEMM: C[M,N] = A[M,K] @ W[N,K]^T (+bias) (+relu) ----------------
template<bool RELU, bool HAS_BIAS>
__global__ __launch_bounds__(256) void gemm_k(const float* __restrict__ A,
                                              const float* __restrict__ W,
                                              const float* __restrict__ bias,
                                              float* __restrict__ C,
                                              int M, int N, int K) {
    __shared__ float As[64][33];
    __shared__ float Ws[64][33];
    const int bx = blockIdx.x * 64;   // N
    const int by = blockIdx.y * 64;   // M
    const int tid = threadIdx.x;
    const int tx = tid & 15;          // col group
    const int ty = tid >> 4;          // row group

    float acc[4][4] = {};

    for (int k0 = 0; k0 < K; k0 += 32) {
        #pragma unroll
        for (int i = tid; i < 64 * 32; i += 256) {
            int r = i >> 5, c = i & 31;
            As[r][c] = A[(size_t)(by + r) * K + k0 + c];
            Ws[r][c] = W[(size_t)(bx + r) * K + k0 + c];
        }
        __syncthreads();
        #pragma unroll
        for (int kk = 0; kk < 32; ++kk) {
            float a[4], w[4];
            #pragma unroll
            for (int i = 0; i < 4; ++i) a[i] = As[ty * 4 + i][kk];
            #pragma unroll
            for (int j = 0; j < 4; ++j) w[j] = Ws[tx * 4 + j][kk];
            #pragma unroll
            for (int i = 0; i < 4; ++i)
                #pragma unroll
                for (int j = 0; j < 4; ++j)
                    acc[i][j] += a[i] * w[j];
        }
        __syncthreads();
    }

    #pragma unroll
    for (int i = 0; i < 4; ++i) {
        int row = by + ty * 4 + i;
        #pragma unroll
        for (int j = 0; j < 4; ++j) {
            int col = bx + tx * 4 + j;
            float v = acc[i][j];
            if (HAS_BIAS) v += bias[col];
            if (RELU) v = fmaxf(v, 0.0f);
            C[(size_t)row * N + col] = v;
        }
    }
}

// ---------------- RoPE in-place ----------------
__global__ __launch_bounds__(256) void rope_k(float* __restrict__ x,
                                              const float* __restrict__ dis,
                                              int rows) {
    int r = blockIdx.x * blockDim.x + threadIdx.x;
    if (r >= rows) return;
    const float* d = dis + (size_t)r * 64;
    float* xr = x + (size_t)r * 64;
    float buf[64];
    #pragma unroll
    for (int j = 0; j < 32; ++j) {
        float s = d[j], c = d[32 + j];
        float x0 = xr[2 * j], x1 = xr[2 * j + 1];
        buf[j]      = x0 * c - x1 * s;
        buf[32 + j] = x1 * c + x0 * s;
    }
    #pragma unroll
    for (int j = 0; j < 64; ++j) xr[j] = buf[j];
}

// ---------------- MFMA flash attention ----------------
// Q,O: (B, LQ, H, 64) f32; K,V: (B, LM, H, 64) f32. scale 1/8.
// Block: 256 threads = 4 waves; block handles 64 query rows for one (b,h).
// Wave handles 16 query rows, full 64-d output, online softmax over 64-key blocks.
template<bool CAUSAL>
__global__ __launch_bounds__(256) void attn_mfma_k(const float* __restrict__ Q,
                                                   const float* __restrict__ K,
                                                   const float* __restrict__ V,
                                                   float* __restrict__ O,
                                                   int H, int LQ, int LM) {
    __shared__ __bf16 Ks[64][72];      // [key][d]
    __shared__ __bf16 Vt[64][72];      // [d][key]  (transposed)
    __shared__ __bf16 Ps[4][16][72];   // per-wave P tile [q_local][key_local]

    const int nqt = LQ / 64;
    const int qt = blockIdx.x % nqt;
    const int h  = (blockIdx.x / nqt) % H;
    const int b  = blockIdx.x / (nqt * H);
    const int q0 = qt * 64;

    const int tid  = threadIdx.x;
    const int wave = tid >> 6;
    const int lane = tid & 63;
    const int frow = lane & 15;   // fragment row (A-row / B-col / D-col)
    const int fgrp = lane >> 4;   // 0..3

    // ---- load Q fragments: lane holds Q[qrow][fgrp*8+j] for chunks d0/d32 ----
    const int qrow = q0 + wave * 16 + frow;
    bf16x8 qf[2];
    {
        const float* qp = Q + (((size_t)b * LQ + qrow) * H + h) * 64 + fgrp * 8;
        #pragma unroll
        for (int c = 0; c < 2; ++c)
            #pragma unroll
            for (int j = 0; j < 8; ++j)
                qf[c][j] = (__bf16)qp[c * 32 + j];
    }

    f32x4 oacc[4] = {};                 // [dtile][reg] ; D-row = fgrp*4+reg
    float mrow[4] = {-INFINITY, -INFINITY, -INFINITY, -INFINITY};
    float lsum[4] = {};

    const int nkb = CAUSAL ? (qt + 1) : (LM / 64);

    for (int kb = 0; kb < nkb; ++kb) {
        const int m0 = kb * 64;
        // ---- stage K (row-major) and V (transposed) as bf16 ----
        {
            const int r  = tid >> 2;
            const int c0 = (tid & 3) * 16;
            const float* kp = K + (((size_t)b * LM + m0 + r) * H + h) * 64 + c0;
            const float* vp = V + (((size_t)b * LM + m0 + r) * H + h) * 64 + c0;
            #pragma unroll
            for (int j = 0; j < 16; ++j) Ks[r][c0 + j] = (__bf16)kp[j];
            #pragma unroll
            for (int j = 0; j < 16; ++j) Vt[c0 + j][r] = (__bf16)vp[j];
        }
        __syncthreads();

        // ---- S = Q K^T : 4 key sub-tiles of 16 ----
        f32x4 s[4];
        #pragma unroll
        for (int n = 0; n < 4; ++n) {
            bf16x8 kf0 = *(const bf16x8*)&Ks[n * 16 + frow][fgrp * 8];
            bf16x8 kf1 = *(const bf16x8*)&Ks[n * 16 + frow][32 + fgrp * 8];
            f32x4 t = {0.f, 0.f, 0.f, 0.f};
            t = __builtin_amdgcn_mfma_f32_16x16x32_bf16(qf[0], kf0, t, 0, 0, 0);
            t = __builtin_amdgcn_mfma_f32_16x16x32_bf16(qf[1], kf1, t, 0, 0, 0);
            s[n] = t;
        }

        // ---- scale + mask ----
        #pragma unroll
        for (int n = 0; n < 4; ++n)
            #pragma unroll
            for (int jj = 0; jj < 4; ++jj) {
                float v = s[n][jj] * 0.125f;
                if (CAUSAL && (m0 + n * 16 + frow) > (q0 + wave * 16 + fgrp * 4 + jj))
                    v = -INFINITY;
                s[n][jj] = v;
            }

        // ---- online softmax (rows live across 16 lanes of same fgrp) ----
        #pragma unroll
        for (int jj = 0; jj < 4; ++jj) {
            float mx = fmaxf(fmaxf(s[0][jj], s[1][jj]), fmaxf(s[2][jj], s[3][jj]));
            #pragma unroll
            for (int msk = 8; msk >= 1; msk >>= 1) mx = fmaxf(mx, __shfl_xor(mx, msk));
            float mnew = fmaxf(mrow[jj], mx);
            float corr = __expf(mrow[jj] - mnew);
            mrow[jj] = mnew;
            float rs = 0.f;
            #pragma unroll
            for (int n = 0; n < 4; ++n) {
                float p = __expf(s[n][jj] - mnew);
                s[n][jj] = p;
                rs += p;
            }
            #pragma unroll
            for (int msk = 8; msk >= 1; msk >>= 1) rs += __shfl_xor(rs, msk);
            lsum[jj] = lsum[jj] * corr + rs;
            #pragma unroll
            for (int n = 0; n < 4; ++n) oacc[n][jj] *= corr;
        }

        // ---- P -> LDS (bf16), transposed into A-fragment layout ----
        #pragma unroll
        for (int n = 0; n < 4; ++n)
            #pragma unroll
            for (int jj = 0; jj < 4; ++jj)
                Ps[wave][fgrp * 4 + jj][n * 16 + frow] = (__bf16)s[n][jj];

        // ---- O += P V : A = P[16 x 64keys], B = V[64keys x 64d] (from Vt) ----
        #pragma unroll
        for (int c = 0; c < 2; ++c) {
            bf16x8 pf = *(const bf16x8*)&Ps[wave][frow][c * 32 + fgrp * 8];
            #pragma unroll
            for (int n = 0; n < 4; ++n) {
                bf16x8 vf = *(const bf16x8*)&Vt[n * 16 + frow][c * 32 + fgrp * 8];
                oacc[n] = __builtin_amdgcn_mfma_f32_16x16x32_bf16(pf, vf, oacc[n], 0, 0, 0);
            }
        }
        __syncthreads();
    }

    // ---- epilogue: normalize and store ----
    #pragma unroll
    for (int jj = 0; jj < 4; ++jj) {
        float inv = 1.0f / lsum[jj];
        int q = q0 + wave * 16 + fgrp * 4 + jj;
        #pragma unroll
        for (int n = 0; n < 4; ++n)
            O[(((size_t)b * LQ + q) * H + h) * 64 + n * 16 + frow] = oacc[n][jj] * inv;
    }
}

// ---------------- deep_norm ----------------
__global__ __launch_bounds__(256) void deepnorm_k(const float* __restrict__ x,
                                                  const float* __restrict__ post,
                                                  const float* __restrict__ g,
                                                  const float* __restrict__ b,
                                                  float* __restrict__ out) {
    int row = blockIdx.x;
    int tid = threadIdx.x;
    const float* xr = x + (size_t)row * 512;
    const float* pr = post + (size_t)row * 512;
    float v0 = xr[tid] * 2.0f + pr[tid];
    float v1 = xr[tid + 256] * 2.0f + pr[tid + 256];

    __shared__ float red[4];
    int wave = tid >> 6, lane = tid & 63;

    float s = v0 + v1;
    #pragma unroll
    for (int o = 32; o >= 1; o >>= 1) s += __shfl_xor(s, o);
    if (lane == 0) red[wave] = s;
    __syncthreads();
    float mean = (red[0] + red[1] + red[2] + red[3]) * (1.0f / 512.0f);

    float d0 = v0 - mean, d1 = v1 - mean;
    float vs = d0 * d0 + d1 * d1;
    #pragma unroll
    for (int o = 32; o >= 1; o >>= 1) vs += __shfl_xor(vs, o);
    __syncthreads();
    if (lane == 0) red[wave] = vs;
    __syncthreads();
    float var = (red[0] + red[1] + red[2] + red[3]) * (1.0f / 512.0f);
    float inv = rsqrtf(var + EPS);

    out[(size_t)row * 512 + tid]       = d0 * inv * g[tid] + b[tid];
    out[(size_t)row * 512 + tid + 256] = d1 * inv * g[tid + 256] + b[tid + 256];
}

__global__ void copy_a_k(const float* __restrict__ A, float* __restrict__ out) {
    out[0] = A[0];
}

// ---------------- launch ----------------
extern "C" void kernel_launch(void* const* d_in, const int* in_sizes, int n_in,
                              void* d_out, int out_size, void* d_ws, size_t ws_size,
                              hipStream_t stream) {
    const float* tgt  = (const float*)d_in[0];
    const float* mem  = (const float*)d_in[1];
    const float* dis_k1 = (const float*)d_in[2];   // glycan_mass
    const float* dis_q1 = (const float*)d_in[3];   // glycan_query_mass
    const float* dis_q2 = (const float*)d_in[4];   // glycan_crossattn_mass
    const float* dis_k2 = (const float*)d_in[5];   // node_mass_emb
    const float* A_in   = (const float*)d_in[10];
    const float* wq1 = (const float*)d_in[11]; const float* bq1 = (const float*)d_in[12];
    const float* wk1 = (const float*)d_in[13]; const float* bk1 = (const float*)d_in[14];
    const float* wv1 = (const float*)d_in[15]; const float* bv1 = (const float*)d_in[16];
    const float* wo1 = (const float*)d_in[17]; const float* bo1 = (const float*)d_in[18];
    const float* ln1g = (const float*)d_in[19]; const float* ln1b = (const float*)d_in[20];
    const float* wq2 = (const float*)d_in[21]; const float* bq2 = (const float*)d_in[22];
    const float* wk2 = (const float*)d_in[23]; const float* bk2 = (const float*)d_in[24];
    const float* wv2 = (const float*)d_in[25]; const float* bv2 = (const float*)d_in[26];
    const float* wo2 = (const float*)d_in[27]; const float* bo2 = (const float*)d_in[28];
    const float* ln2g = (const float*)d_in[29]; const float* ln2b = (const float*)d_in[30];
    const float* wff1 = (const float*)d_in[31]; const float* wff2 = (const float*)d_in[32];
    const float* ln3g = (const float*)d_in[33]; const float* ln3b = (const float*)d_in[34];

    auto at = [&](size_t mb) { return (float*)((char*)d_ws + mb * 1024 * 1024); };
    float* x1   = at(0);
    float* x2   = at(4);
    float* post = at(8);
    float* q1   = at(12);
    float* k1   = at(16);
    float* v1   = at(20);
    float* att1 = at(24);
    float* q2   = at(12);
    float* k2   = at(20);
    float* v2   = at(36);
    float* att2 = at(52);
    float* ffh  = at(12);

    float* out = (float*)d_out;

    // ---- Phase 1: self-attention ----
    gemm_k<false, true><<<dim3(512 / 64, 2048 / 64), 256, 0, stream>>>(tgt, wq1, bq1, q1, 2048, 512, 512);
    gemm_k<false, true><<<dim3(512 / 64, 2048 / 64), 256, 0, stream>>>(tgt, wk1, bk1, k1, 2048, 512, 512);
    gemm_k<false, true><<<dim3(512 / 64, 2048 / 64), 256, 0, stream>>>(tgt, wv1, bv1, v1, 2048, 512, 512);
    rope_k<<<16384 / 256, 256, 0, stream>>>(q1, dis_q1, 16384);
    rope_k<<<16384 / 256, 256, 0, stream>>>(k1, dis_k1, 16384);
    attn_mfma_k<true><<<4 * 8 * 8, 256, 0, stream>>>(q1, k1, v1, att1, 8, 512, 512);
    gemm_k<false, true><<<dim3(512 / 64, 2048 / 64), 256, 0, stream>>>(att1, wo1, bo1, post, 2048, 512, 512);
    deepnorm_k<<<2048, 256, 0, stream>>>(tgt, post, ln1g, ln1b, x1);

    // ---- Phase 2: cross-attention ----
    gemm_k<false, true><<<dim3(1024 / 64, 2048 / 64), 256, 0, stream>>>(x1, wq2, bq2, q2, 2048, 1024, 512);
    gemm_k<false, true><<<dim3(1024 / 64, 4096 / 64), 256, 0, stream>>>(mem, wk2, bk2, k2, 4096, 1024, 512);
    gemm_k<false, true><<<dim3(1024 / 64, 4096 / 64), 256, 0, stream>>>(mem, wv2, bv2, v2, 4096, 1024, 512);
    rope_k<<<32768 / 256, 256, 0, stream>>>(q2, dis_q2, 32768);
    rope_k<<<65536 / 256, 256, 0, stream>>>(k2, dis_k2, 65536);
    attn_mfma_k<false><<<4 * 16 * 8, 256, 0, stream>>>(q2, k2, v2, att2, 16, 512, 1024);
    gemm_k<false, true><<<dim3(512 / 64, 2048 / 64), 256, 0, stream>>>(att2, wo2, bo2, post, 2048, 512, 1024);
    deepnorm_k<<<2048, 256, 0, stream>>>(x1, post, ln2g, ln2b, x2);

    // ---- Phase 3: FFN ----
    gemm_k<true, false><<<dim3(2048 / 64, 2048 / 64), 256, 0, stream>>>(x2, wff1, nullptr, ffh, 2048, 2048, 512);
    gemm_k<false, false><<<dim3(512 / 64, 2048 / 64), 256, 0, stream>>>(ffh, wff2, nullptr, post, 2048, 512, 2048);
    deepnorm_k<<<2048, 256, 0, stream>>>(x2, post, ln3g, ln3b, out);

    copy_a_k<<<1, 1, 0, stream>>>(A_in, out + 2048 * 512);
}

// Round 3
// 270.564 us; speedup vs baseline: 9.7641x; 5.3759x over previous
//
#include <hip/hip_runtime.h>
#include <hip/hip_bf16.h>
#include <math.h>

#define EPS 1e-5f

typedef __attribute__((ext_vector_type(8))) __bf16 bf16x8;
typedef __attribute__((ext_vector_type(4))) float f32x4;

// ---------------- fused f32 -> bf16 conversion (weights + activations) ----------------
struct CvtJobs {
    const float* src[12];
    __bf16* dst[12];
    int off[13];   // prefix sums, units of 8-element groups
};

__global__ __launch_bounds__(256) void cvt_k(CvtJobs J, int total) {
    int g = blockIdx.x * 256 + threadIdx.x;
    if (g >= total) return;
    int j = 0;
    #pragma unroll
    for (int t = 0; t < 11; ++t) j += (g >= J.off[t + 1]) ? 1 : 0;
    int lg = g - J.off[j];
    const float* s = J.src[j] + (size_t)lg * 8;
    float4 a = *(const float4*)s;
    float4 b = *(const float4*)(s + 4);
    bf16x8 o;
    o[0] = (__bf16)a.x; o[1] = (__bf16)a.y; o[2] = (__bf16)a.z; o[3] = (__bf16)a.w;
    o[4] = (__bf16)b.x; o[5] = (__bf16)b.y; o[6] = (__bf16)b.z; o[7] = (__bf16)b.w;
    *(bf16x8*)(J.dst[j] + (size_t)lg * 8) = o;
}

// ---------------- bf16 MFMA GEMM: C[M,N] = A[M,K] @ W[N,K]^T (+bias)(+relu) ----------------
// m97 structure: 128x128 tile, BK=64, 4 waves (2x2 of 64x64), global_load_lds staging.
template<typename OutT, bool RELU, bool HAS_BIAS>
__global__ __launch_bounds__(256) void gemm_bf16_k(const __bf16* __restrict__ A,
                                                   const __bf16* __restrict__ W,
                                                   const float* __restrict__ bias,
                                                   OutT* __restrict__ C,
                                                   int M, int N, int K) {
    __shared__ __bf16 As[128 * 64];
    __shared__ __bf16 Ws[128 * 64];

    const int tid  = threadIdx.x;
    const int wave = tid >> 6;
    const int lane = tid & 63;
    const int frow = lane & 15;
    const int fgrp = lane >> 4;
    const int bx = blockIdx.x * 128;
    const int by = blockIdx.y * 128;
    const int wr = (wave >> 1) * 64;   // wave row offset in tile
    const int wc = (wave & 1) * 64;    // wave col offset in tile

    const int ldr = lane >> 3;         // 0..7 row within 8-row chunk
    const int ldc = (lane & 7) * 8;    // col (elements)

    f32x4 acc[4][4] = {};

    for (int k0 = 0; k0 < K; k0 += 64) {
        #pragma unroll
        for (int it = 0; it < 4; ++it) {
            int chunk = it * 4 + wave;         // 0..15, wave-uniform
            int r = chunk * 8 + ldr;
            const __bf16* ga = A + (size_t)(by + r) * K + k0 + ldc;
            const __bf16* gw = W + (size_t)(bx + r) * K + k0 + ldc;
            __builtin_amdgcn_global_load_lds(
                (const __attribute__((address_space(1))) unsigned int*)ga,
                (__attribute__((address_space(3))) unsigned int*)(As + chunk * 512),
                16, 0, 0);
            __builtin_amdgcn_global_load_lds(
                (const __attribute__((address_space(1))) unsigned int*)gw,
                (__attribute__((address_space(3))) unsigned int*)(Ws + chunk * 512),
                16, 0, 0);
        }
        __syncthreads();

        #pragma unroll
        for (int kk = 0; kk < 2; ++kk) {
            bf16x8 af[4], wf[4];
            #pragma unroll
            for (int i = 0; i < 4; ++i)
                af[i] = *(const bf16x8*)&As[(wr + i * 16 + frow) * 64 + kk * 32 + fgrp * 8];
            #pragma unroll
            for (int j = 0; j < 4; ++j)
                wf[j] = *(const bf16x8*)&Ws[(wc + j * 16 + frow) * 64 + kk * 32 + fgrp * 8];
            #pragma unroll
            for (int i = 0; i < 4; ++i)
                #pragma unroll
                for (int j = 0; j < 4; ++j)
                    acc[i][j] = __builtin_amdgcn_mfma_f32_16x16x32_bf16(af[i], wf[j], acc[i][j], 0, 0, 0);
        }
        __syncthreads();
    }

    #pragma unroll
    for (int i = 0; i < 4; ++i) {
        #pragma unroll
        for (int jj = 0; jj < 4; ++jj) {
            int row = by + wr + i * 16 + fgrp * 4 + jj;
            #pragma unroll
            for (int j = 0; j < 4; ++j) {
                int col = bx + wc + j * 16 + frow;
                float v = acc[i][j][jj];
                if (HAS_BIAS) v += bias[col];
                if (RELU) v = fmaxf(v, 0.0f);
                C[(size_t)row * N + col] = (OutT)v;
            }
        }
    }
}

// ---------------- RoPE in-place on bf16 rows ----------------
__global__ __launch_bounds__(256) void rope_bf16_k(__bf16* __restrict__ x,
                                                   const float* __restrict__ dis,
                                                   int rows, int hshift, int rowstride) {
    int r = blockIdx.x * 256 + threadIdx.x;
    if (r >= rows) return;
    int h = r & ((1 << hshift) - 1);
    int rt = r >> hshift;
    __bf16* xr = x + (size_t)rt * rowstride + h * 64;
    const float* d = dis + (size_t)r * 64;
    float xv[64];
    #pragma unroll
    for (int j = 0; j < 8; ++j) {
        bf16x8 v = *(const bf16x8*)(xr + j * 8);
        #pragma unroll
        for (int t = 0; t < 8; ++t) xv[j * 8 + t] = (float)v[t];
    }
    float ov[64];
    #pragma unroll
    for (int j = 0; j < 32; ++j) {
        float s = d[j], c = d[32 + j];
        float x0 = xv[2 * j], x1 = xv[2 * j + 1];
        ov[j]      = x0 * c - x1 * s;
        ov[32 + j] = x1 * c + x0 * s;
    }
    #pragma unroll
    for (int j = 0; j < 8; ++j) {
        bf16x8 v;
        #pragma unroll
        for (int t = 0; t < 8; ++t) v[t] = (__bf16)ov[j * 8 + t];
        *(bf16x8*)(xr + j * 8) = v;
    }
}

// ---------------- MFMA flash attention (bf16 in, bf16 out) ----------------
// Q: rows (b, t) with qstride elems/row, head h at col h*64. Same for K/V/O.
template<bool CAUSAL>
__global__ __launch_bounds__(256) void attn_bf16_k(const __bf16* __restrict__ Q,
                                                   const __bf16* __restrict__ K,
                                                   const __bf16* __restrict__ V,
                                                   __bf16* __restrict__ O,
                                                   int H, int LQ, int LM,
                                                   int qstride, int kvstride, int ostride) {
    __shared__ __bf16 Ks[64][72];
    __shared__ __bf16 Vt[64][72];
    __shared__ __bf16 Ps[4][16][72];

    const int nqt = LQ / 64;
    const int qt = blockIdx.x % nqt;
    const int h  = (blockIdx.x / nqt) % H;
    const int b  = blockIdx.x / (nqt * H);
    const int q0 = qt * 64;

    const int tid  = threadIdx.x;
    const int wave = tid >> 6;
    const int lane = tid & 63;
    const int frow = lane & 15;
    const int fgrp = lane >> 4;

    const int qrow = q0 + wave * 16 + frow;
    bf16x8 qf[2];
    {
        const __bf16* qp = Q + ((size_t)b * LQ + qrow) * qstride + h * 64 + fgrp * 8;
        qf[0] = *(const bf16x8*)qp;
        qf[1] = *(const bf16x8*)(qp + 32);
    }

    f32x4 oacc[4] = {};
    float mrow[4] = {-INFINITY, -INFINITY, -INFINITY, -INFINITY};
    float lsum[4] = {};

    const int nkb = CAUSAL ? (qt + 1) : (LM / 64);

    for (int kb = 0; kb < nkb; ++kb) {
        const int m0 = kb * 64;
        {
            const int r  = tid >> 2;
            const int c0 = (tid & 3) * 16;
            const __bf16* kp = K + ((size_t)b * LM + m0 + r) * kvstride + h * 64 + c0;
            const __bf16* vp = V + ((size_t)b * LM + m0 + r) * kvstride + h * 64 + c0;
            bf16x8 kv0 = *(const bf16x8*)kp;
            bf16x8 kv1 = *(const bf16x8*)(kp + 8);
            *(bf16x8*)&Ks[r][c0]     = kv0;
            *(bf16x8*)&Ks[r][c0 + 8] = kv1;
            bf16x8 vv0 = *(const bf16x8*)vp;
            bf16x8 vv1 = *(const bf16x8*)(vp + 8);
            #pragma unroll
            for (int j = 0; j < 8; ++j) {
                Vt[c0 + j][r]     = vv0[j];
                Vt[c0 + 8 + j][r] = vv1[j];
            }
        }
        __syncthreads();

        f32x4 s[4];
        #pragma unroll
        for (int n = 0; n < 4; ++n) {
            bf16x8 kf0 = *(const bf16x8*)&Ks[n * 16 + frow][fgrp * 8];
            bf16x8 kf1 = *(const bf16x8*)&Ks[n * 16 + frow][32 + fgrp * 8];
            f32x4 t = {0.f, 0.f, 0.f, 0.f};
            t = __builtin_amdgcn_mfma_f32_16x16x32_bf16(qf[0], kf0, t, 0, 0, 0);
            t = __builtin_amdgcn_mfma_f32_16x16x32_bf16(qf[1], kf1, t, 0, 0, 0);
            s[n] = t;
        }

        #pragma unroll
        for (int n = 0; n < 4; ++n)
            #pragma unroll
            for (int jj = 0; jj < 4; ++jj) {
                float v = s[n][jj] * 0.125f;
                if (CAUSAL && (m0 + n * 16 + frow) > (q0 + wave * 16 + fgrp * 4 + jj))
                    v = -INFINITY;
                s[n][jj] = v;
            }

        #pragma unroll
        for (int jj = 0; jj < 4; ++jj) {
            float mx = fmaxf(fmaxf(s[0][jj], s[1][jj]), fmaxf(s[2][jj], s[3][jj]));
            #pragma unroll
            for (int msk = 8; msk >= 1; msk >>= 1) mx = fmaxf(mx, __shfl_xor(mx, msk));
            float mnew = fmaxf(mrow[jj], mx);
            float corr = __expf(mrow[jj] - mnew);
            mrow[jj] = mnew;
            float rs = 0.f;
            #pragma unroll
            for (int n = 0; n < 4; ++n) {
                float p = __expf(s[n][jj] - mnew);
                s[n][jj] = p;
                rs += p;
            }
            #pragma unroll
            for (int msk = 8; msk >= 1; msk >>= 1) rs += __shfl_xor(rs, msk);
            lsum[jj] = lsum[jj] * corr + rs;
            #pragma unroll
            for (int n = 0; n < 4; ++n) oacc[n][jj] *= corr;
        }

        #pragma unroll
        for (int n = 0; n < 4; ++n)
            #pragma unroll
            for (int jj = 0; jj < 4; ++jj)
                Ps[wave][fgrp * 4 + jj][n * 16 + frow] = (__bf16)s[n][jj];

        #pragma unroll
        for (int c = 0; c < 2; ++c) {
            bf16x8 pf = *(const bf16x8*)&Ps[wave][frow][c * 32 + fgrp * 8];
            #pragma unroll
            for (int n = 0; n < 4; ++n) {
                bf16x8 vf = *(const bf16x8*)&Vt[n * 16 + frow][c * 32 + fgrp * 8];
                oacc[n] = __builtin_amdgcn_mfma_f32_16x16x32_bf16(pf, vf, oacc[n], 0, 0, 0);
            }
        }
        __syncthreads();
    }

    #pragma unroll
    for (int jj = 0; jj < 4; ++jj) {
        float inv = 1.0f / lsum[jj];
        int q = q0 + wave * 16 + fgrp * 4 + jj;
        #pragma unroll
        for (int n = 0; n < 4; ++n)
            O[((size_t)b * LQ + q) * ostride + h * 64 + n * 16 + frow] = (__bf16)(oacc[n][jj] * inv);
    }
}

// ---------------- deep_norm: out = LN(x*2 + post)*g + b ; optional bf16 copy ----------------
template<bool WRITE_BF>
__global__ __launch_bounds__(256) void deepnorm_k(const float* __restrict__ x,
                                                  const float* __restrict__ post,
                                                  const float* __restrict__ g,
                                                  const float* __restrict__ b,
                                                  float* __restrict__ out,
                                                  __bf16* __restrict__ out_bf) {
    int row = blockIdx.x;
    int tid = threadIdx.x;
    const float* xr = x + (size_t)row * 512;
    const float* pr = post + (size_t)row * 512;
    float v0 = xr[tid] * 2.0f + pr[tid];
    float v1 = xr[tid + 256] * 2.0f + pr[tid + 256];

    __shared__ float red[4];
    int wave = tid >> 6, lane = tid & 63;

    float s = v0 + v1;
    #pragma unroll
    for (int o = 32; o >= 1; o >>= 1) s += __shfl_xor(s, o);
    if (lane == 0) red[wave] = s;
    __syncthreads();
    float mean = (red[0] + red[1] + red[2] + red[3]) * (1.0f / 512.0f);

    float d0 = v0 - mean, d1 = v1 - mean;
    float vs = d0 * d0 + d1 * d1;
    #pragma unroll
    for (int o = 32; o >= 1; o >>= 1) vs += __shfl_xor(vs, o);
    __syncthreads();
    if (lane == 0) red[wave] = vs;
    __syncthreads();
    float var = (red[0] + red[1] + red[2] + red[3]) * (1.0f / 512.0f);
    float inv = rsqrtf(var + EPS);

    float o0 = d0 * inv * g[tid] + b[tid];
    float o1 = d1 * inv * g[tid + 256] + b[tid + 256];
    out[(size_t)row * 512 + tid]       = o0;
    out[(size_t)row * 512 + tid + 256] = o1;
    if (WRITE_BF) {
        out_bf[(size_t)row * 512 + tid]       = (__bf16)o0;
        out_bf[(size_t)row * 512 + tid + 256] = (__bf16)o1;
    }
}

__global__ void copy_a_k(const float* __restrict__ A, float* __restrict__ out) {
    out[0] = A[0];
}

// ---------------- launch ----------------
extern "C" void kernel_launch(void* const* d_in, const int* in_sizes, int n_in,
                              void* d_out, int out_size, void* d_ws, size_t ws_size,
                              hipStream_t stream) {
    const float* tgt  = (const float*)d_in[0];
    const float* mem  = (const float*)d_in[1];
    const float* dis_k1 = (const float*)d_in[2];
    const float* dis_q1 = (const float*)d_in[3];
    const float* dis_q2 = (const float*)d_in[4];
    const float* dis_k2 = (const float*)d_in[5];
    const float* A_in   = (const float*)d_in[10];
    const float* wq1 = (const float*)d_in[11]; const float* bq1 = (const float*)d_in[12];
    const float* wk1 = (const float*)d_in[13]; const float* bk1 = (const float*)d_in[14];
    const float* wv1 = (const float*)d_in[15]; const float* bv1 = (const float*)d_in[16];
    const float* wo1 = (const float*)d_in[17]; const float* bo1 = (const float*)d_in[18];
    const float* ln1g = (const float*)d_in[19]; const float* ln1b = (const float*)d_in[20];
    const float* wq2 = (const float*)d_in[21]; const float* bq2 = (const float*)d_in[22];
    const float* wk2 = (const float*)d_in[23]; const float* bk2 = (const float*)d_in[24];
    const float* wv2 = (const float*)d_in[25]; const float* bv2 = (const float*)d_in[26];
    const float* wo2 = (const float*)d_in[27]; const float* bo2 = (const float*)d_in[28];
    const float* ln2g = (const float*)d_in[29]; const float* ln2b = (const float*)d_in[30];
    const float* wff1 = (const float*)d_in[31]; const float* wff2 = (const float*)d_in[32];
    const float* ln3g = (const float*)d_in[33]; const float* ln3b = (const float*)d_in[34];

    char* ws = (char*)d_ws;
    auto MB = [&](size_t mb) { return ws + mb * 1024 * 1024; };

    __bf16* wqkv1_bf = (__bf16*)MB(0);     // [1536][512]
    __bf16* wo1_bf   = (__bf16*)MB(2);     // [512][512]
    __bf16* wq2_bf   = (__bf16*)MB(3);     // [1024][512]
    __bf16* wk2_bf   = (__bf16*)MB(4);     // [1024][512]
    __bf16* wv2_bf   = (__bf16*)MB(5);     // [1024][512]
    __bf16* wo2_bf   = (__bf16*)MB(6);     // [512][1024]
    __bf16* wff1_bf  = (__bf16*)MB(7);     // [2048][512]
    __bf16* wff2_bf  = (__bf16*)MB(9);     // [512][2048]
    float*  bqkv1    = (float*)MB(11);     // [1536]
    __bf16* tgt_bf   = (__bf16*)MB(12);    // [2048][512]
    __bf16* mem_bf   = (__bf16*)MB(14);    // [4096][512]
    __bf16* qkv1_bf  = (__bf16*)MB(18);    // [2048][1536]
    __bf16* att1_bf  = (__bf16*)MB(24);    // [2048][512]
    float*  post     = (float*)MB(26);     // [2048][512]
    float*  x1       = (float*)MB(30);     // [2048][512]
    __bf16* x1_bf    = (__bf16*)MB(34);    // [2048][512]
    __bf16* q2_bf    = (__bf16*)MB(18);    // [2048][1024]  (qkv1 dead after attn1)
    __bf16* k2_bf    = (__bf16*)MB(36);    // [4096][1024]
    __bf16* v2_bf    = (__bf16*)MB(44);    // [4096][1024]
    __bf16* att2_bf  = (__bf16*)MB(52);    // [2048][1024]
    float*  x2       = (float*)MB(18);     // [2048][512]   (q2 dead after attn2)
    __bf16* x2_bf    = (__bf16*)MB(22);    // [2048][512]
    __bf16* ffh_bf   = (__bf16*)MB(36);    // [2048][2048]  (k2 dead after attn2)

    float* out = (float*)d_out;

    // ---- conversions (one fused kernel) ----
    CvtJobs J;
    const float* srcs[12] = {tgt, mem, wq1, wk1, wv1, wo1, wq2, wk2, wv2, wo2, wff1, wff2};
    __bf16* dsts[12] = {tgt_bf, mem_bf, wqkv1_bf, wqkv1_bf + 262144, wqkv1_bf + 524288,
                        wo1_bf, wq2_bf, wk2_bf, wv2_bf, wo2_bf, wff1_bf, wff2_bf};
    int sizes[12] = {2048 * 512, 4096 * 512, 512 * 512, 512 * 512, 512 * 512, 512 * 512,
                     1024 * 512, 1024 * 512, 1024 * 512, 1024 * 512, 2048 * 512, 512 * 2048};
    int acc = 0;
    for (int i = 0; i < 12; ++i) { J.src[i] = srcs[i]; J.dst[i] = dsts[i]; J.off[i] = acc; acc += sizes[i] / 8; }
    J.off[12] = acc;
    cvt_k<<<(acc + 255) / 256, 256, 0, stream>>>(J, acc);

    hipMemcpyAsync(bqkv1,        bq1, 512 * sizeof(float), hipMemcpyDeviceToDevice, stream);
    hipMemcpyAsync(bqkv1 + 512,  bk1, 512 * sizeof(float), hipMemcpyDeviceToDevice, stream);
    hipMemcpyAsync(bqkv1 + 1024, bv1, 512 * sizeof(float), hipMemcpyDeviceToDevice, stream);

    // ---- Phase 1: self-attention ----
    gemm_bf16_k<__bf16, false, true><<<dim3(12, 16), 256, 0, stream>>>(tgt_bf, wqkv1_bf, bqkv1, qkv1_bf, 2048, 1536, 512);
    rope_bf16_k<<<64, 256, 0, stream>>>(qkv1_bf,       dis_q1, 16384, 3, 1536);
    rope_bf16_k<<<64, 256, 0, stream>>>(qkv1_bf + 512, dis_k1, 16384, 3, 1536);
    attn_bf16_k<true><<<4 * 8 * 8, 256, 0, stream>>>(qkv1_bf, qkv1_bf + 512, qkv1_bf + 1024, att1_bf,
                                                     8, 512, 512, 1536, 1536, 512);
    gemm_bf16_k<float, false, true><<<dim3(4, 16), 256, 0, stream>>>(att1_bf, wo1_bf, bo1, post, 2048, 512, 512);
    deepnorm_k<true><<<2048, 256, 0, stream>>>(tgt, post, ln1g, ln1b, x1, x1_bf);

    // ---- Phase 2: cross-attention ----
    gemm_bf16_k<__bf16, false, true><<<dim3(8, 16), 256, 0, stream>>>(x1_bf, wq2_bf, bq2, q2_bf, 2048, 1024, 512);
    gemm_bf16_k<__bf16, false, true><<<dim3(8, 32), 256, 0, stream>>>(mem_bf, wk2_bf, bk2, k2_bf, 4096, 1024, 512);
    gemm_bf16_k<__bf16, false, true><<<dim3(8, 32), 256, 0, stream>>>(mem_bf, wv2_bf, bv2, v2_bf, 4096, 1024, 512);
    rope_bf16_k<<<128, 256, 0, stream>>>(q2_bf, dis_q2, 32768, 4, 1024);
    rope_bf16_k<<<256, 256, 0, stream>>>(k2_bf, dis_k2, 65536, 4, 1024);
    attn_bf16_k<false><<<4 * 16 * 8, 256, 0, stream>>>(q2_bf, k2_bf, v2_bf, att2_bf,
                                                       16, 512, 1024, 1024, 1024, 1024);
    gemm_bf16_k<float, false, true><<<dim3(4, 16), 256, 0, stream>>>(att2_bf, wo2_bf, bo2, post, 2048, 512, 1024);
    deepnorm_k<true><<<2048, 256, 0, stream>>>(x1, post, ln2g, ln2b, x2, x2_bf);

    // ---- Phase 3: FFN ----
    gemm_bf16_k<__bf16, true, false><<<dim3(16, 16), 256, 0, stream>>>(x2_bf, wff1_bf, nullptr, ffh_bf, 2048, 2048, 512);
    gemm_bf16_k<float, false, false><<<dim3(4, 16), 256, 0, stream>>>(ffh_bf, wff2_bf, nullptr, post, 2048, 512, 2048);
    deepnorm_k<false><<<2048, 256, 0, stream>>>(x2, post, ln3g, ln3b, out, nullptr);

    copy_a_k<<<1, 1, 0, stream>>>(A_in, out + 2048 * 512);
}

// Round 4
// 196.381 us; speedup vs baseline: 13.4525x; 1.3778x over previous
//
#include <hip/hip_runtime.h>
#include <hip/hip_bf16.h>
#include <math.h>

#define EPS 1e-5f

typedef __attribute__((ext_vector_type(8))) __bf16 bf16x8;
typedef __attribute__((ext_vector_type(4))) float f32x4;

// ---------------- fused f32 -> bf16 conversion ----------------
struct CvtJobs {
    const float* src[12];
    __bf16* dst[12];
    int off[13];
};

__global__ __launch_bounds__(256) void cvt_k(CvtJobs J, int total) {
    int g = blockIdx.x * 256 + threadIdx.x;
    if (g >= total) return;
    int j = 0;
    #pragma unroll
    for (int t = 0; t < 11; ++t) j += (g >= J.off[t + 1]) ? 1 : 0;
    int lg = g - J.off[j];
    const float* s = J.src[j] + (size_t)lg * 8;
    float4 a = *(const float4*)s;
    float4 b = *(const float4*)(s + 4);
    bf16x8 o;
    o[0] = (__bf16)a.x; o[1] = (__bf16)a.y; o[2] = (__bf16)a.z; o[3] = (__bf16)a.w;
    o[4] = (__bf16)b.x; o[5] = (__bf16)b.y; o[6] = (__bf16)b.z; o[7] = (__bf16)b.w;
    *(bf16x8*)(J.dst[j] + (size_t)lg * 8) = o;
}

// ---------------- bf16 MFMA GEMM, tile BTxBT, XCD swizzle, multi-bias ----------------
template<int BT, typename OutT, bool RELU, bool HAS_BIAS>
__global__ __launch_bounds__(256) void gemm_bf16_k(const __bf16* __restrict__ A,
                                                   const __bf16* __restrict__ W,
                                                   const float* __restrict__ b0,
                                                   const float* __restrict__ b1,
                                                   const float* __restrict__ b2,
                                                   int bshift,
                                                   OutT* __restrict__ C,
                                                   int M, int N, int K) {
    constexpr int NI = BT / 32;
    __shared__ __bf16 As[BT * 64];
    __shared__ __bf16 Ws[BT * 64];

    const int tid  = threadIdx.x;
    const int wave = tid >> 6;
    const int lane = tid & 63;
    const int frow = lane & 15;
    const int fgrp = lane >> 4;

    // XCD-bijective swizzle (grid always %8==0 here)
    const int nb  = gridDim.x * gridDim.y;
    const int bid = blockIdx.y * gridDim.x + blockIdx.x;
    const int v   = (bid & 7) * (nb >> 3) + (bid >> 3);
    const int bx  = (v % gridDim.x) * BT;
    const int by  = (v / gridDim.x) * BT;

    const int wr = (wave >> 1) * (BT / 2);
    const int wc = (wave & 1) * (BT / 2);
    const int ldr = lane >> 3;
    const int ldc = (lane & 7) * 8;

    f32x4 acc[NI][NI] = {};

    for (int k0 = 0; k0 < K; k0 += 64) {
        #pragma unroll
        for (int it = 0; it < NI; ++it) {
            int chunk = it * 4 + wave;
            int r = chunk * 8 + ldr;
            const __bf16* ga = A + (size_t)(by + r) * K + k0 + ldc;
            const __bf16* gw = W + (size_t)(bx + r) * K + k0 + ldc;
            __builtin_amdgcn_global_load_lds(
                (const __attribute__((address_space(1))) unsigned int*)ga,
                (__attribute__((address_space(3))) unsigned int*)(As + chunk * 512),
                16, 0, 0);
            __builtin_amdgcn_global_load_lds(
                (const __attribute__((address_space(1))) unsigned int*)gw,
                (__attribute__((address_space(3))) unsigned int*)(Ws + chunk * 512),
                16, 0, 0);
        }
        __syncthreads();

        #pragma unroll
        for (int kk = 0; kk < 2; ++kk) {
            bf16x8 af[NI], wf[NI];
            #pragma unroll
            for (int i = 0; i < NI; ++i)
                af[i] = *(const bf16x8*)&As[(wr + i * 16 + frow) * 64 + kk * 32 + fgrp * 8];
            #pragma unroll
            for (int j = 0; j < NI; ++j)
                wf[j] = *(const bf16x8*)&Ws[(wc + j * 16 + frow) * 64 + kk * 32 + fgrp * 8];
            #pragma unroll
            for (int i = 0; i < NI; ++i)
                #pragma unroll
                for (int j = 0; j < NI; ++j)
                    acc[i][j] = __builtin_amdgcn_mfma_f32_16x16x32_bf16(af[i], wf[j], acc[i][j], 0, 0, 0);
        }
        __syncthreads();
    }

    #pragma unroll
    for (int i = 0; i < NI; ++i) {
        #pragma unroll
        for (int jj = 0; jj < 4; ++jj) {
            int row = by + wr + i * 16 + fgrp * 4 + jj;
            #pragma unroll
            for (int j = 0; j < NI; ++j) {
                int col = bx + wc + j * 16 + frow;
                float val = acc[i][j][jj];
                if (HAS_BIAS) {
                    int sel = col >> bshift;
                    const float* bp = sel == 0 ? b0 : (sel == 1 ? b1 : b2);
                    val += bp[col & (int)((1u << bshift) - 1)];
                }
                if (RELU) val = fmaxf(val, 0.0f);
                C[(size_t)row * N + col] = (OutT)val;
            }
        }
    }
}

// ---------------- MFMA flash attention, fused RoPE, XCD swizzle ----------------
// Q,K,V,O bf16; dis f32 (s=d[0:32], c=d[32:64]); scale 1/8.
// Block: 4 waves x 16 q-rows = 64 queries for one (b,h).
template<bool CAUSAL>
__global__ __launch_bounds__(256) void attn_bf16_k(const __bf16* __restrict__ Q,
                                                   const __bf16* __restrict__ K,
                                                   const __bf16* __restrict__ V,
                                                   __bf16* __restrict__ O,
                                                   const float* __restrict__ disQ,
                                                   const float* __restrict__ disK,
                                                   int H, int LQ, int LM,
                                                   int qstride, int kvstride, int ostride) {
    __shared__ __bf16 Ks[64 * 72];
    __shared__ __bf16 Vt[64 * 72];
    __shared__ __bf16 Ps[4 * 16 * 72];

    const int nqt = LQ >> 6;
    const int nb  = gridDim.x;
    const int bid = blockIdx.x;
    const int v   = (bid & 7) * (nb >> 3) + (bid >> 3);
    const int qt = v % nqt;
    const int h  = (v / nqt) % H;
    const int b  = v / (nqt * H);
    const int q0 = qt * 64;

    const int tid  = threadIdx.x;
    const int wave = tid >> 6;
    const int lane = tid & 63;
    const int frow = lane & 15;
    const int fgrp = lane >> 4;

    // ---- Q load + fused RoPE ----
    const int qrow = q0 + wave * 16 + frow;
    bf16x8 qf0, qf1;
    {
        const __bf16* qp = Q + ((size_t)b * LQ + qrow) * qstride + h * 64 + fgrp * 16;
        bf16x8 xa = *(const bf16x8*)qp;
        bf16x8 xb = *(const bf16x8*)(qp + 8);
        float xs[16];
        #pragma unroll
        for (int t = 0; t < 8; ++t) { xs[t] = (float)xa[t]; xs[8 + t] = (float)xb[t]; }
        const float* dq = disQ + (((size_t)b * LQ + qrow) * H + h) * 64 + fgrp * 8;
        #pragma unroll
        for (int t = 0; t < 8; ++t) {
            float sv = dq[t], cv = dq[32 + t];
            float x0 = xs[2 * t], x1 = xs[2 * t + 1];
            qf0[t] = (__bf16)(x0 * cv - x1 * sv);
            qf1[t] = (__bf16)(x1 * cv + x0 * sv);
        }
    }

    f32x4 oacc[4] = {};
    float mrow[4] = {-INFINITY, -INFINITY, -INFINITY, -INFINITY};
    float lsum[4] = {};

    const int nkb = CAUSAL ? (qt + 1) : (LM >> 6);
    const int r   = tid >> 2;        // staging row 0..63
    const int c0q = tid & 3;         // staging col quarter

    for (int kb = 0; kb < nkb; ++kb) {
        const int m0 = kb * 64;
        // ---- stage K with fused RoPE (row-major) ----
        {
            const __bf16* kp = K + ((size_t)b * LM + m0 + r) * kvstride + h * 64 + c0q * 16;
            bf16x8 xa = *(const bf16x8*)kp;
            bf16x8 xb = *(const bf16x8*)(kp + 8);
            float xs[16];
            #pragma unroll
            for (int t = 0; t < 8; ++t) { xs[t] = (float)xa[t]; xs[8 + t] = (float)xb[t]; }
            const float* dk = disK + (((size_t)b * LM + m0 + r) * H + h) * 64 + c0q * 8;
            bf16x8 o0, o1;
            #pragma unroll
            for (int t = 0; t < 8; ++t) {
                float sv = dk[t], cv = dk[32 + t];
                float x0 = xs[2 * t], x1 = xs[2 * t + 1];
                o0[t] = (__bf16)(x0 * cv - x1 * sv);
                o1[t] = (__bf16)(x1 * cv + x0 * sv);
            }
            *(bf16x8*)&Ks[r * 72 + c0q * 8]      = o0;
            *(bf16x8*)&Ks[r * 72 + 32 + c0q * 8] = o1;
        }
        // ---- stage V transposed with XOR swizzle (conflict-free) ----
        {
            const __bf16* vp = V + ((size_t)b * LM + m0 + r) * kvstride + h * 64 + c0q * 16;
            bf16x8 va = *(const bf16x8*)vp;
            bf16x8 vb = *(const bf16x8*)(vp + 8);
            int kphys = (r & 7) + 8 * ((r >> 3) ^ (2 * c0q));
            #pragma unroll
            for (int j = 0; j < 8; ++j) {
                Vt[(c0q * 16 + j) * 72 + kphys]     = va[j];
                Vt[(c0q * 16 + 8 + j) * 72 + kphys] = vb[j];
            }
        }
        __syncthreads();

        // ---- S = Q K^T ----
        f32x4 s[4];
        #pragma unroll
        for (int n = 0; n < 4; ++n) {
            bf16x8 kf0 = *(const bf16x8*)&Ks[(n * 16 + frow) * 72 + fgrp * 8];
            bf16x8 kf1 = *(const bf16x8*)&Ks[(n * 16 + frow) * 72 + 32 + fgrp * 8];
            f32x4 t = {0.f, 0.f, 0.f, 0.f};
            t = __builtin_amdgcn_mfma_f32_16x16x32_bf16(qf0, kf0, t, 0, 0, 0);
            t = __builtin_amdgcn_mfma_f32_16x16x32_bf16(qf1, kf1, t, 0, 0, 0);
            s[n] = t;
        }

        // ---- scale + causal mask ----
        #pragma unroll
        for (int n = 0; n < 4; ++n)
            #pragma unroll
            for (int jj = 0; jj < 4; ++jj) {
                float val = s[n][jj] * 0.125f;
                if (CAUSAL && (m0 + n * 16 + frow) > (q0 + wave * 16 + fgrp * 4 + jj))
                    val = -INFINITY;
                s[n][jj] = val;
            }

        // ---- online softmax with defer-max (THR=8) ----
        float mxv[4];
        int allsmall = 1;
        #pragma unroll
        for (int jj = 0; jj < 4; ++jj) {
            float mx = fmaxf(fmaxf(s[0][jj], s[1][jj]), fmaxf(s[2][jj], s[3][jj]));
            #pragma unroll
            for (int msk = 8; msk >= 1; msk >>= 1) mx = fmaxf(mx, __shfl_xor(mx, msk));
            mxv[jj] = mx;
            allsmall &= (mx <= mrow[jj] + 8.0f) ? 1 : 0;
        }
        if (__all(allsmall)) {
            #pragma unroll
            for (int jj = 0; jj < 4; ++jj) {
                float rs = 0.f;
                #pragma unroll
                for (int n = 0; n < 4; ++n) {
                    float p = __expf(s[n][jj] - mrow[jj]);
                    s[n][jj] = p;
                    rs += p;
                }
                #pragma unroll
                for (int msk = 8; msk >= 1; msk >>= 1) rs += __shfl_xor(rs, msk);
                lsum[jj] += rs;
            }
        } else {
            #pragma unroll
            for (int jj = 0; jj < 4; ++jj) {
                float mnew = fmaxf(mrow[jj], mxv[jj]);
                float corr = __expf(mrow[jj] - mnew);
                mrow[jj] = mnew;
                float rs = 0.f;
                #pragma unroll
                for (int n = 0; n < 4; ++n) {
                    float p = __expf(s[n][jj] - mnew);
                    s[n][jj] = p;
                    rs += p;
                }
                #pragma unroll
                for (int msk = 8; msk >= 1; msk >>= 1) rs += __shfl_xor(rs, msk);
                lsum[jj] = lsum[jj] * corr + rs;
                #pragma unroll
                for (int n = 0; n < 4; ++n) oacc[n][jj] *= corr;
            }
        }

        // ---- P -> LDS (swizzled, conflict-free) ----
        #pragma unroll
        for (int n = 0; n < 4; ++n)
            #pragma unroll
            for (int jj = 0; jj < 4; ++jj) {
                int q = fgrp * 4 + jj;
                int kidx = (frow & 7) + 8 * (((2 * n) + (frow >> 3)) ^ (2 * ((q >> 3) & 1)));
                Ps[wave * 1152 + q * 72 + kidx] = (__bf16)s[n][jj];
            }

        // ---- O += P V ----
        #pragma unroll
        for (int c = 0; c < 2; ++c) {
            int pblk = (c * 4 + fgrp) ^ (2 * ((frow >> 3) & 1));
            bf16x8 pf = *(const bf16x8*)&Ps[wave * 1152 + frow * 72 + 8 * pblk];
            #pragma unroll
            for (int n = 0; n < 4; ++n) {
                int vblk = (c * 4 + fgrp) ^ (2 * n);
                bf16x8 vf = *(const bf16x8*)&Vt[(n * 16 + frow) * 72 + 8 * vblk];
                oacc[n] = __builtin_amdgcn_mfma_f32_16x16x32_bf16(pf, vf, oacc[n], 0, 0, 0);
            }
        }
        __syncthreads();
    }

    // ---- epilogue ----
    #pragma unroll
    for (int jj = 0; jj < 4; ++jj) {
        float inv = 1.0f / lsum[jj];
        int q = q0 + wave * 16 + fgrp * 4 + jj;
        #pragma unroll
        for (int n = 0; n < 4; ++n)
            O[((size_t)b * LQ + q) * ostride + h * 64 + n * 16 + frow] = (__bf16)(oacc[n][jj] * inv);
    }
}

// ---------------- deep_norm ----------------
template<bool WRITE_BF>
__global__ __launch_bounds__(256) void deepnorm_k(const float* __restrict__ x,
                                                  const float* __restrict__ post,
                                                  const float* __restrict__ g,
                                                  const float* __restrict__ b,
                                                  float* __restrict__ out,
                                                  __bf16* __restrict__ out_bf) {
    int row = blockIdx.x;
    int tid = threadIdx.x;
    const float* xr = x + (size_t)row * 512;
    const float* pr = post + (size_t)row * 512;
    float v0 = xr[tid] * 2.0f + pr[tid];
    float v1 = xr[tid + 256] * 2.0f + pr[tid + 256];

    __shared__ float red[4];
    int wave = tid >> 6, lane = tid & 63;

    float s = v0 + v1;
    #pragma unroll
    for (int o = 32; o >= 1; o >>= 1) s += __shfl_xor(s, o);
    if (lane == 0) red[wave] = s;
    __syncthreads();
    float mean = (red[0] + red[1] + red[2] + red[3]) * (1.0f / 512.0f);

    float d0 = v0 - mean, d1 = v1 - mean;
    float vs = d0 * d0 + d1 * d1;
    #pragma unroll
    for (int o = 32; o >= 1; o >>= 1) vs += __shfl_xor(vs, o);
    __syncthreads();
    if (lane == 0) red[wave] = vs;
    __syncthreads();
    float var = (red[0] + red[1] + red[2] + red[3]) * (1.0f / 512.0f);
    float inv = rsqrtf(var + EPS);

    float o0 = d0 * inv * g[tid] + b[tid];
    float o1 = d1 * inv * g[tid + 256] + b[tid + 256];
    out[(size_t)row * 512 + tid]       = o0;
    out[(size_t)row * 512 + tid + 256] = o1;
    if (WRITE_BF) {
        out_bf[(size_t)row * 512 + tid]       = (__bf16)o0;
        out_bf[(size_t)row * 512 + tid + 256] = (__bf16)o1;
    }
}

__global__ void copy_a_k(const float* __restrict__ A, float* __restrict__ out) {
    out[0] = A[0];
}

// ---------------- launch ----------------
extern "C" void kernel_launch(void* const* d_in, const int* in_sizes, int n_in,
                              void* d_out, int out_size, void* d_ws, size_t ws_size,
                              hipStream_t stream) {
    const float* tgt  = (const float*)d_in[0];
    const float* mem  = (const float*)d_in[1];
    const float* dis_k1 = (const float*)d_in[2];
    const float* dis_q1 = (const float*)d_in[3];
    const float* dis_q2 = (const float*)d_in[4];
    const float* dis_k2 = (const float*)d_in[5];
    const float* A_in   = (const float*)d_in[10];
    const float* wq1 = (const float*)d_in[11]; const float* bq1 = (const float*)d_in[12];
    const float* wk1 = (const float*)d_in[13]; const float* bk1 = (const float*)d_in[14];
    const float* wv1 = (const float*)d_in[15]; const float* bv1 = (const float*)d_in[16];
    const float* wo1 = (const float*)d_in[17]; const float* bo1 = (const float*)d_in[18];
    const float* ln1g = (const float*)d_in[19]; const float* ln1b = (const float*)d_in[20];
    const float* wq2 = (const float*)d_in[21]; const float* bq2 = (const float*)d_in[22];
    const float* wk2 = (const float*)d_in[23]; const float* bk2 = (const float*)d_in[24];
    const float* wv2 = (const float*)d_in[25]; const float* bv2 = (const float*)d_in[26];
    const float* wo2 = (const float*)d_in[27]; const float* bo2 = (const float*)d_in[28];
    const float* ln2g = (const float*)d_in[29]; const float* ln2b = (const float*)d_in[30];
    const float* wff1 = (const float*)d_in[31]; const float* wff2 = (const float*)d_in[32];
    const float* ln3g = (const float*)d_in[33]; const float* ln3b = (const float*)d_in[34];

    char* ws = (char*)d_ws;
    auto MB = [&](size_t mb) { return ws + mb * 1024 * 1024; };

    __bf16* wqkv1_bf = (__bf16*)MB(0);     // [1536][512]
    __bf16* wo1_bf   = (__bf16*)MB(2);     // [512][512]
    __bf16* wq2_bf   = (__bf16*)MB(3);     // [1024][512]
    __bf16* wkv2_bf  = (__bf16*)MB(4);     // [2048][512] (wk2 rows 0..1023, wv2 rows 1024..2047)
    __bf16* wo2_bf   = (__bf16*)MB(6);     // [512][1024]
    __bf16* wff1_bf  = (__bf16*)MB(7);     // [2048][512]
    __bf16* wff2_bf  = (__bf16*)MB(9);     // [512][2048]
    __bf16* tgt_bf   = (__bf16*)MB(11);    // [2048][512]; reused as x1_bf later
    __bf16* mem_bf   = (__bf16*)MB(13);    // [4096][512]
    __bf16* qkv1_bf  = (__bf16*)MB(17);    // [2048][1536]; reused as q2_bf later
    __bf16* att1_bf  = (__bf16*)MB(23);    // [2048][512]
    float*  post     = (float*)MB(25);     // [2048][512]
    float*  x1       = (float*)MB(29);     // [2048][512]
    __bf16* kv2_bf   = (__bf16*)MB(33);    // [4096][2048]; reused as ffh later
    __bf16* att2_bf  = (__bf16*)MB(49);    // [2048][1024]
    float*  x2       = (float*)MB(53);     // [2048][512]
    __bf16* x2_bf    = (__bf16*)MB(57);    // [2048][512]
    __bf16* x1_bf    = tgt_bf;
    __bf16* q2_bf    = qkv1_bf;
    __bf16* ffh_bf   = kv2_bf;

    float* out = (float*)d_out;

    // ---- conversions ----
    CvtJobs J;
    const float* srcs[12] = {tgt, mem, wq1, wk1, wv1, wo1, wq2, wk2, wv2, wo2, wff1, wff2};
    __bf16* dsts[12] = {tgt_bf, mem_bf, wqkv1_bf, wqkv1_bf + 262144, wqkv1_bf + 524288,
                        wo1_bf, wq2_bf, wkv2_bf, wkv2_bf + 524288, wo2_bf, wff1_bf, wff2_bf};
    int sizes[12] = {2048 * 512, 4096 * 512, 512 * 512, 512 * 512, 512 * 512, 512 * 512,
                     1024 * 512, 1024 * 512, 1024 * 512, 1024 * 512, 2048 * 512, 512 * 2048};
    int acc = 0;
    for (int i = 0; i < 12; ++i) { J.src[i] = srcs[i]; J.dst[i] = dsts[i]; J.off[i] = acc; acc += sizes[i] / 8; }
    J.off[12] = acc;
    cvt_k<<<(acc + 255) / 256, 256, 0, stream>>>(J, acc);

    // ---- Phase 1: self-attention ----
    gemm_bf16_k<128, __bf16, false, true><<<dim3(12, 16), 256, 0, stream>>>(
        tgt_bf, wqkv1_bf, bq1, bk1, bv1, 9, qkv1_bf, 2048, 1536, 512);
    attn_bf16_k<true><<<256, 256, 0, stream>>>(qkv1_bf, qkv1_bf + 512, qkv1_bf + 1024, att1_bf,
                                               dis_q1, dis_k1, 8, 512, 512, 1536, 1536, 512);
    gemm_bf16_k<64, float, false, true><<<dim3(8, 32), 256, 0, stream>>>(
        att1_bf, wo1_bf, bo1, bo1, bo1, 31, post, 2048, 512, 512);
    deepnorm_k<true><<<2048, 256, 0, stream>>>(tgt, post, ln1g, ln1b, x1, x1_bf);

    // ---- Phase 2: cross-attention ----
    gemm_bf16_k<64, __bf16, false, true><<<dim3(16, 32), 256, 0, stream>>>(
        x1_bf, wq2_bf, bq2, bq2, bq2, 31, q2_bf, 2048, 1024, 512);
    gemm_bf16_k<128, __bf16, false, true><<<dim3(16, 32), 256, 0, stream>>>(
        mem_bf, wkv2_bf, bk2, bv2, bv2, 10, kv2_bf, 4096, 2048, 512);
    attn_bf16_k<false><<<512, 256, 0, stream>>>(q2_bf, kv2_bf, kv2_bf + 1024, att2_bf,
                                                dis_q2, dis_k2, 16, 512, 1024, 1024, 2048, 1024);
    gemm_bf16_k<64, float, false, true><<<dim3(8, 32), 256, 0, stream>>>(
        att2_bf, wo2_bf, bo2, bo2, bo2, 31, post, 2048, 512, 1024);
    deepnorm_k<true><<<2048, 256, 0, stream>>>(x1, post, ln2g, ln2b, x2, x2_bf);

    // ---- Phase 3: FFN ----
    gemm_bf16_k<128, __bf16, true, false><<<dim3(16, 16), 256, 0, stream>>>(
        x2_bf, wff1_bf, nullptr, nullptr, nullptr, 31, ffh_bf, 2048, 2048, 512);
    gemm_bf16_k<64, float, false, false><<<dim3(8, 32), 256, 0, stream>>>(
        ffh_bf, wff2_bf, nullptr, nullptr, nullptr, 31, post, 2048, 512, 2048);
    deepnorm_k<false><<<2048, 256, 0, stream>>>(x2, post, ln3g, ln3b, out, nullptr);

    copy_a_k<<<1, 1, 0, stream>>>(A_in, out + 2048 * 512);
}